// Round 9
// baseline (864.526 us; speedup 1.0000x reference)
//
#include <hip/hip_runtime.h>
#include <math.h>

// ---------------------------------------------------------------------------
// FlashSVD LLaMA block, round 9: base = round-6 (proven 527us). The three
// ~86us dispatches (SILU, MUL, dV) switch to gemmr: barrier-free, LDS-free
// register GEMM (wave-independent streams; manual cur/nxt register prefetch).
// Diagnosis r6-r8: K-steps stall on HBM-tail latency under lockstep barriers;
// independent waves at 4 blocks/CU hide it statistically.
// ---------------------------------------------------------------------------

typedef __bf16 bf16;
typedef __bf16 bf16x8 __attribute__((ext_vector_type(8)));
typedef __bf16 bf16x4 __attribute__((ext_vector_type(4)));
typedef float  f32x4  __attribute__((ext_vector_type(4)));

#define EPI_BF16   0
#define EPI_BF16T  1   // transposed bf16 store (V in [d][t] layout)
#define EPI_F32ADD 2   // fp32 store with residual add
#define EPI_SILU1  3   // store silu(acc) bf16
#define EPI_MUL    4   // RMW: C *= acc (bf16)
#define EPI_PART   5   // fp32 partial plane store (split-K)

__device__ __forceinline__ void gld16(const void* g, void* l) {
    __builtin_amdgcn_global_load_lds(
        (const __attribute__((address_space(1))) unsigned int*)g,
        (__attribute__((address_space(3))) unsigned int*)l, 16, 0, 0);
}

// ---------------------------------------------------------------------------
// gemmr: LDS-free, barrier-free register GEMM. A bf16 [M,K], B fp32 [N,K].
// 128x128 tile, 4 waves (2x2), wave tile 64x64, K-step 32. Each wave is an
// independent stream: fragment loads straight from global (L1/L2 serve the
// intra-block duplication), fp32->bf16 convert in regs, next-step prefetch
// via explicit cur/nxt register sets (static indexing).
// Grid: dim3(nwg,1,z); XCD-bijective remap; bm=id%gx, bn=id/gx.
// ---------------------------------------------------------------------------
template<int EPI>
__global__ __launch_bounds__(256)
void gemmr(const bf16* __restrict__ A, int lda, long sA,
           const float* __restrict__ B, int ldb, long sB, const float* __restrict__ B2,
           void* __restrict__ Cv, int ldc, long sC,
           const float* __restrict__ R, int Kc, int nsplit, int gx)
{
    const int lane = threadIdx.x & 63, w = threadIdx.x >> 6;
    const int wr = w >> 1, wc = w & 1;

    int id = blockIdx.x;
    {   // bijective XCD remap (m204)
        const int nwg = gridDim.x;
        int q = nwg >> 3, rr = nwg & 7;
        int xcd = id & 7, off = id >> 3;
        id = (xcd < rr ? xcd * (q + 1) : rr * (q + 1) + (xcd - rr) * q) + off;
    }
    const int bm = id % gx, bn = id / gx, bz = blockIdx.z;
    const int ks = bz % nsplit, zb = bz / nsplit;

    const float* Bp = (B2 != nullptr && zb != 0) ? B2 : B;
    const int g = lane >> 4, r = lane & 15;

    // per-lane row bases (fragment row = base + m*16 rows)
    const bf16*  Aw = A  + (long)zb * sA + (long)(bm * 128 + wr * 64 + r) * lda + (long)ks * Kc + g * 8;
    const float* Bw = Bp + (long)zb * sB + (long)(bn * 128 + wc * 64 + r) * ldb + (long)ks * Kc + g * 8;

    f32x4 acc[4][4] = {};

    bf16x8 a0, a1, a2, a3;
    f32x4  bl0, bh0, bl1, bh1, bl2, bh2, bl3, bh3;

    auto loadA = [&](int k0, bf16x8& x0, bf16x8& x1, bf16x8& x2, bf16x8& x3) {
        x0 = *(const bf16x8*)(Aw + 0 * 16 * lda + k0);
        x1 = *(const bf16x8*)(Aw + 1 * 16 * lda + k0);
        x2 = *(const bf16x8*)(Aw + 2 * 16 * lda + k0);
        x3 = *(const bf16x8*)(Aw + 3 * 16 * lda + k0);
    };
    auto loadB = [&](int k0, f32x4& l0, f32x4& h0, f32x4& l1, f32x4& h1,
                     f32x4& l2, f32x4& h2, f32x4& l3, f32x4& h3) {
        const float* b0 = Bw + 0 * 16 * ldb + k0;
        const float* b1 = Bw + 1 * 16 * ldb + k0;
        const float* b2 = Bw + 2 * 16 * ldb + k0;
        const float* b3 = Bw + 3 * 16 * ldb + k0;
        l0 = *(const f32x4*)b0; h0 = *(const f32x4*)(b0 + 4);
        l1 = *(const f32x4*)b1; h1 = *(const f32x4*)(b1 + 4);
        l2 = *(const f32x4*)b2; h2 = *(const f32x4*)(b2 + 4);
        l3 = *(const f32x4*)b3; h3 = *(const f32x4*)(b3 + 4);
    };

    loadA(0, a0, a1, a2, a3);
    loadB(0, bl0, bh0, bl1, bh1, bl2, bh2, bl3, bh3);

    for (int k0 = 0; k0 < Kc; k0 += 32) {
        bf16x8 na0, na1, na2, na3;
        f32x4  nl0, nh0, nl1, nh1, nl2, nh2, nl3, nh3;
        const bool more = (k0 + 32 < Kc);
        if (more) {                       // prefetch next step during MFMA
            loadA(k0 + 32, na0, na1, na2, na3);
            loadB(k0 + 32, nl0, nh0, nl1, nh1, nl2, nh2, nl3, nh3);
        }

        bf16x8 af[4] = {a0, a1, a2, a3};
        bf16x8 bfr[4];
        bfr[0] = bf16x8{(bf16)bl0[0],(bf16)bl0[1],(bf16)bl0[2],(bf16)bl0[3],
                        (bf16)bh0[0],(bf16)bh0[1],(bf16)bh0[2],(bf16)bh0[3]};
        bfr[1] = bf16x8{(bf16)bl1[0],(bf16)bl1[1],(bf16)bl1[2],(bf16)bl1[3],
                        (bf16)bh1[0],(bf16)bh1[1],(bf16)bh1[2],(bf16)bh1[3]};
        bfr[2] = bf16x8{(bf16)bl2[0],(bf16)bl2[1],(bf16)bl2[2],(bf16)bl2[3],
                        (bf16)bh2[0],(bf16)bh2[1],(bf16)bh2[2],(bf16)bh2[3]};
        bfr[3] = bf16x8{(bf16)bl3[0],(bf16)bl3[1],(bf16)bl3[2],(bf16)bl3[3],
                        (bf16)bh3[0],(bf16)bh3[1],(bf16)bh3[2],(bf16)bh3[3]};

        #pragma unroll
        for (int m = 0; m < 4; m++)
            #pragma unroll
            for (int n = 0; n < 4; n++)
                acc[m][n] = __builtin_amdgcn_mfma_f32_16x16x32_bf16(af[m], bfr[n], acc[m][n], 0, 0, 0);

        if (more) {
            a0 = na0; a1 = na1; a2 = na2; a3 = na3;
            bl0 = nl0; bh0 = nh0; bl1 = nl1; bh1 = nh1;
            bl2 = nl2; bh2 = nh2; bl3 = nl3; bh3 = nh3;
        }
    }

    // epilogue: C layout col = lane&15, row = (lane>>4)*4 + j
    #pragma unroll
    for (int m = 0; m < 4; m++) {
        #pragma unroll
        for (int n = 0; n < 4; n++) {
            const int row0 = bm * 128 + wr * 64 + m * 16 + g * 4;
            const int col  = bn * 128 + wc * 64 + n * 16 + r;
            #pragma unroll
            for (int j = 0; j < 4; j++) {
                float v = acc[m][n][j];
                long row = row0 + j;
                if constexpr (EPI == EPI_BF16) {
                    ((bf16*)Cv)[(long)zb * sC + row * (long)ldc + col] = (bf16)v;
                } else if constexpr (EPI == EPI_BF16T) {
                    ((bf16*)Cv)[(long)zb * sC + (long)col * ldc + row] = (bf16)v;
                } else if constexpr (EPI == EPI_F32ADD) {
                    long idx = row * (long)ldc + col;
                    ((float*)Cv)[idx] = v + R[idx];
                } else if constexpr (EPI == EPI_PART) {
                    ((float*)Cv)[(long)bz * sC + row * (long)ldc + col] = v;
                } else if constexpr (EPI == EPI_SILU1) {
                    ((bf16*)Cv)[row * (long)ldc + col] = (bf16)(v / (1.f + __expf(-v)));
                } else { // EPI_MUL
                    bf16* p = &((bf16*)Cv)[row * (long)ldc + col];
                    *p = (bf16)((float)*p * v);
                }
            }
        }
    }
}

// ---------------------------------------------------------------------------
// gemm3f (round-6, proven): 256-thread single-buffered 48KB, 2 barriers/step.
// ---------------------------------------------------------------------------
template<int EPI>
__global__ __launch_bounds__(256)
void gemm3f(const bf16* __restrict__ A, int lda, long sA,
            const float* __restrict__ B, int ldb, long sB, const float* __restrict__ B2,
            void* __restrict__ Cv, int ldc, long sC,
            const float* __restrict__ R, int Kc, int nsplit, int gx)
{
    __shared__ __align__(16) bf16  As[128 * 64];   // 16 KB
    __shared__ __align__(16) float Bs[128 * 64];   // 32 KB

    const int tid = threadIdx.x, lane = tid & 63, w = tid >> 6;
    const int wr = w >> 1, wc = w & 1;

    int id = blockIdx.x;
    {
        const int nwg = gridDim.x;
        int q = nwg >> 3, rr = nwg & 7;
        int xcd = id & 7, off = id >> 3;
        id = (xcd < rr ? xcd * (q + 1) : rr * (q + 1) + (xcd - rr) * q) + off;
    }
    const int bm = id % gx, bn = id / gx, bz = blockIdx.z;
    const int ks = bz % nsplit, zb = bz / nsplit;

    const float* Bp = (B2 != nullptr && zb != 0) ? B2 : B;
    const bf16*  Ab = A  + (long)zb * sA + (long)(bm * 128) * lda + (long)ks * Kc;
    const float* Bb = Bp + (long)zb * sB + (long)(bn * 128) * ldb + (long)ks * Kc;

    const int g = lane >> 4, r = lane & 15;
    f32x4 acc[4][4] = {};
    const int nt = Kc >> 6;

    for (int t = 0; t < nt; t++) {
        if (t) __syncthreads();
        const bf16*  At = Ab + t * 64;
        const float* Bt = Bb + t * 64;
        #pragma unroll
        for (int i = 0; i < 4; i++) {
            int cb = w * 256 + i * 64, ci = cb + lane;
            int row = ci >> 3, col = ((ci & 7) ^ (row & 7)) * 8;
            gld16(At + (long)row * lda + col, &As[cb * 8]);
        }
        #pragma unroll
        for (int i = 0; i < 8; i++) {
            int cb = w * 512 + i * 64, ci = cb + lane;
            int row = ci >> 4, col = ((ci & 15) ^ (row & 15)) * 4;
            gld16(Bt + (long)row * ldb + col, &Bs[cb * 4]);
        }
        __syncthreads();
        #pragma unroll
        for (int kk = 0; kk < 2; kk++) {
            bf16x8 af[4], bfr[4];
            #pragma unroll
            for (int m = 0; m < 4; m++) {
                int row = wr * 64 + m * 16 + r;
                af[m] = *(const bf16x8*)&As[row * 64 + (((kk * 4 + g) ^ (row & 7)) * 8)];
            }
            #pragma unroll
            for (int n = 0; n < 4; n++) {
                int row = wc * 64 + n * 16 + r;
                int c0 = kk * 8 + g * 2;
                f32x4 lo = *(const f32x4*)&Bs[row * 64 + (((c0    ) ^ (row & 15)) * 4)];
                f32x4 hi = *(const f32x4*)&Bs[row * 64 + (((c0 + 1) ^ (row & 15)) * 4)];
                bfr[n] = bf16x8{(bf16)lo[0], (bf16)lo[1], (bf16)lo[2], (bf16)lo[3],
                                (bf16)hi[0], (bf16)hi[1], (bf16)hi[2], (bf16)hi[3]};
            }
            #pragma unroll
            for (int m = 0; m < 4; m++)
                #pragma unroll
                for (int n = 0; n < 4; n++)
                    acc[m][n] = __builtin_amdgcn_mfma_f32_16x16x32_bf16(af[m], bfr[n], acc[m][n], 0, 0, 0);
        }
    }

    #pragma unroll
    for (int m = 0; m < 4; m++) {
        #pragma unroll
        for (int n = 0; n < 4; n++) {
            const int row0 = bm * 128 + wr * 64 + m * 16 + g * 4;
            const int col  = bn * 128 + wc * 64 + n * 16 + r;
            #pragma unroll
            for (int j = 0; j < 4; j++) {
                float v = acc[m][n][j];
                long row = row0 + j;
                if constexpr (EPI == EPI_BF16) {
                    ((bf16*)Cv)[(long)zb * sC + row * (long)ldc + col] = (bf16)v;
                } else if constexpr (EPI == EPI_BF16T) {
                    ((bf16*)Cv)[(long)zb * sC + (long)col * ldc + row] = (bf16)v;
                } else if constexpr (EPI == EPI_F32ADD) {
                    long idx = row * (long)ldc + col;
                    ((float*)Cv)[idx] = v + R[idx];
                } else if constexpr (EPI == EPI_PART) {
                    ((float*)Cv)[(long)bz * sC + row * (long)ldc + col] = v;
                } else if constexpr (EPI == EPI_SILU1) {
                    ((bf16*)Cv)[row * (long)ldc + col] = (bf16)(v / (1.f + __expf(-v)));
                } else {
                    bf16* p = &((bf16*)Cv)[row * (long)ldc + col];
                    *p = (bf16)((float)*p * v);
                }
            }
        }
    }
}

// ---------------------------------------------------------------------------
// gemm2 (fallback for small workspace): fp32 B converted in staging, dbuf.
// ---------------------------------------------------------------------------
template<int EPI>
__global__ __launch_bounds__(256)
void gemm2(const bf16* __restrict__ A, int lda, long sA,
           const float* __restrict__ B, int ldb, long sB, const float* __restrict__ B2,
           void* __restrict__ Cv, int ldc, long sC,
           const float* __restrict__ R, int Kc, int nsplit)
{
    __shared__ __align__(16) bf16 As[2][128 * 64];
    __shared__ __align__(16) bf16 Bs[2][128 * 64];

    const int tid = threadIdx.x, lane = tid & 63, w = tid >> 6;
    const int wr = w >> 1, wc = w & 1;
    const int bm = blockIdx.x, bn = blockIdx.y, bz = blockIdx.z;
    const int ks = bz % nsplit, zb = bz / nsplit;

    const float* Bp = (B2 != nullptr && zb != 0) ? B2 : B;
    const bf16*  Ab = A  + (long)zb * sA + (long)(bm * 128) * lda + (long)ks * Kc;
    const float* Bb = Bp + (long)zb * sB + (long)(bn * 128) * ldb + (long)ks * Kc;

    const int g = lane >> 4, r = lane & 15;
    f32x4 acc[4][4] = {};
    const int nt = Kc >> 6;
    int cur = 0;

    {
        #pragma unroll
        for (int i = 0; i < 4; i++) {
            int cb = i * 256 + w * 64, ci = cb + lane;
            int arow = ci >> 3, acol = ((ci & 7) ^ (arow & 7)) * 8;
            gld16(Ab + (long)arow * lda + acol, &As[0][cb * 8]);
        }
        float4 fb[8];
        #pragma unroll
        for (int i = 0; i < 8; i++) {
            int p = i * 256 + tid;
            fb[i] = *(const float4*)(Bb + (long)(p >> 4) * ldb + (p & 15) * 4);
        }
        #pragma unroll
        for (int i = 0; i < 8; i++) {
            int p = i * 256 + tid, brow = p >> 4, c4 = p & 15;
            bf16x4 h = {(bf16)fb[i].x, (bf16)fb[i].y, (bf16)fb[i].z, (bf16)fb[i].w};
            *(bf16x4*)&Bs[0][brow * 64 + (((c4 >> 1) ^ (brow & 7)) * 8) + (c4 & 1) * 4] = h;
        }
    }
    __syncthreads();

    for (int t = 0; t < nt; t++) {
        float4 fb[8];
        if (t + 1 < nt) {
            const bf16* An = Ab + (t + 1) * 64;
            #pragma unroll
            for (int i = 0; i < 4; i++) {
                int cb = i * 256 + w * 64, ci = cb + lane;
                int arow = ci >> 3, acol = ((ci & 7) ^ (arow & 7)) * 8;
                gld16(An + (long)arow * lda + acol, &As[cur ^ 1][cb * 8]);
            }
            const float* Bn = Bb + (t + 1) * 64;
            #pragma unroll
            for (int i = 0; i < 8; i++) {
                int p = i * 256 + tid;
                fb[i] = *(const float4*)(Bn + (long)(p >> 4) * ldb + (p & 15) * 4);
            }
        }
        #pragma unroll
        for (int kk = 0; kk < 2; kk++) {
            bf16x8 af[4], bfr[4];
            #pragma unroll
            for (int m = 0; m < 4; m++) {
                int row = wr * 64 + m * 16 + r;
                af[m] = *(const bf16x8*)&As[cur][row * 64 + (((kk * 4 + g) ^ (row & 7)) * 8)];
            }
            #pragma unroll
            for (int n = 0; n < 4; n++) {
                int row = wc * 64 + n * 16 + r;
                bfr[n] = *(const bf16x8*)&Bs[cur][row * 64 + (((kk * 4 + g) ^ (row & 7)) * 8)];
            }
            #pragma unroll
            for (int m = 0; m < 4; m++)
                #pragma unroll
                for (int n = 0; n < 4; n++)
                    acc[m][n] = __builtin_amdgcn_mfma_f32_16x16x32_bf16(af[m], bfr[n], acc[m][n], 0, 0, 0);
        }
        if (t + 1 < nt) {
            #pragma unroll
            for (int i = 0; i < 8; i++) {
                int p = i * 256 + tid, brow = p >> 4, c4 = p & 15;
                bf16x4 h = {(bf16)fb[i].x, (bf16)fb[i].y, (bf16)fb[i].z, (bf16)fb[i].w};
                *(bf16x4*)&Bs[cur ^ 1][brow * 64 + (((c4 >> 1) ^ (brow & 7)) * 8) + (c4 & 1) * 4] = h;
            }
            __syncthreads();
            cur ^= 1;
        }
    }

    #pragma unroll
    for (int m = 0; m < 4; m++) {
        #pragma unroll
        for (int n = 0; n < 4; n++) {
            const int row0 = bm * 128 + wr * 64 + m * 16 + g * 4;
            const int col  = bn * 128 + wc * 64 + n * 16 + r;
            #pragma unroll
            for (int j = 0; j < 4; j++) {
                float v = acc[m][n][j];
                long row = row0 + j;
                if constexpr (EPI == EPI_BF16) {
                    ((bf16*)Cv)[(long)zb * sC + row * (long)ldc + col] = (bf16)v;
                } else if constexpr (EPI == EPI_BF16T) {
                    ((bf16*)Cv)[(long)zb * sC + (long)col * ldc + row] = (bf16)v;
                } else if constexpr (EPI == EPI_F32ADD) {
                    long idx = row * (long)ldc + col;
                    ((float*)Cv)[idx] = v + R[idx];
                } else if constexpr (EPI == EPI_PART) {
                    ((float*)Cv)[(long)bz * sC + row * (long)ldc + col] = v;
                } else if constexpr (EPI == EPI_SILU1) {
                    ((bf16*)Cv)[row * (long)ldc + col] = (bf16)(v / (1.f + __expf(-v)));
                } else {
                    bf16* p = &((bf16*)Cv)[row * (long)ldc + col];
                    *p = (bf16)((float)*p * v);
                }
            }
        }
    }
}

// ---------------------------------------------------------------------------
__global__ __launch_bounds__(256)
void reduce_k(const float* __restrict__ part, long pe, int np, bf16* __restrict__ out)
{
    long i = ((long)blockIdx.x * 256 + threadIdx.x) * 4;
    float4 s = *(const float4*)&part[i];
    for (int p = 1; p < np; p++) {
        float4 v = *(const float4*)&part[(long)p * pe + i];
        s.x += v.x; s.y += v.y; s.z += v.z; s.w += v.w;
    }
    bf16x4 o = {(bf16)s.x, (bf16)s.y, (bf16)s.z, (bf16)s.w};
    *(bf16x4*)&out[i] = o;
}

__global__ __launch_bounds__(256)
void rmsnorm_k(const float* __restrict__ x, const float* __restrict__ w,
               bf16* __restrict__ out)
{
    const int D = 4096;
    const long row = blockIdx.x;
    const float* xr = x + row * D;
    float4 v[4];
    float ss = 0.f;
    #pragma unroll
    for (int k = 0; k < 4; k++) {
        v[k] = *(const float4*)&xr[threadIdx.x * 4 + k * 1024];
        ss += v[k].x * v[k].x + v[k].y * v[k].y + v[k].z * v[k].z + v[k].w * v[k].w;
    }
    #pragma unroll
    for (int o = 32; o > 0; o >>= 1) ss += __shfl_down(ss, o);
    __shared__ float red[4];
    if ((threadIdx.x & 63) == 0) red[threadIdx.x >> 6] = ss;
    __syncthreads();
    float rs = rsqrtf((red[0] + red[1] + red[2] + red[3]) / D + 1e-5f);
    #pragma unroll
    for (int k = 0; k < 4; k++) {
        int i = threadIdx.x * 4 + k * 1024;
        float4 wv = *(const float4*)&w[i];
        bf16x4 o4 = {(bf16)(v[k].x * rs * wv.x), (bf16)(v[k].y * rs * wv.y),
                     (bf16)(v[k].z * rs * wv.z), (bf16)(v[k].w * rs * wv.w)};
        *(bf16x4*)&out[row * D + i] = o4;
    }
}

__global__ __launch_bounds__(256)
void rope_table_k(float* cs, float* sn)
{
    int idx = blockIdx.x * blockDim.x + threadIdx.x;  // 1024*64
    int t = idx >> 6, i = idx & 63;
    float inv = powf(10000.0f, -(2.0f * i) / 128.0f);
    float a = (float)t * inv;
    cs[idx] = cosf(a);
    sn[idx] = sinf(a);
}

__global__ __launch_bounds__(256)
void rope_k(bf16* qk, const float* __restrict__ cs, const float* __restrict__ sn)
{
    long idx = (long)blockIdx.x * blockDim.x + threadIdx.x;
    int d = idx & 63;
    long ht = idx >> 6;
    int t = (int)(ht & 1023);
    bf16* p = qk + ht * 128;
    float x1 = (float)p[d], x2 = (float)p[d + 64];
    int i1 = d >> 1;
    float c1 = cs[t * 64 + i1],      s1 = sn[t * 64 + i1];
    float c2 = cs[t * 64 + 32 + i1], s2 = sn[t * 64 + 32 + i1];
    p[d]      = (bf16)(x1 * c1 - x2 * s1);
    p[d + 64] = (bf16)(x2 * c2 + x1 * s2);
}

// ---------------------------------------------------------------------------
// Flash attention (causal, GQA 4:1), 4 waves x 16 q-rows, KV tile 64.
// ---------------------------------------------------------------------------
__global__ __launch_bounds__(256)
void attn_k(const bf16* __restrict__ Q,   // [32][1024][128]
            const bf16* __restrict__ Kb,  // [8][1024][128]
            const bf16* __restrict__ Vt,  // [8][128][1024]
            bf16* __restrict__ O)         // [1024][4096]
{
    const int T = 1024;
    __shared__ __align__(16) bf16 Ks[64][128];
    __shared__ __align__(16) bf16 Vs[128][64];
    __shared__ __align__(16) bf16 Ps[4][16][72];

    const int qt = blockIdx.x, h = blockIdx.y, hk = h >> 2;
    const int tid = threadIdx.x, lane = tid & 63, w = tid >> 6;
    const int g = lane >> 4, r = lane & 15;
    const int qrow0 = qt * 64 + w * 16;

    bf16x8 qf[4];
    const bf16* qp = Q + ((long)h * T + qrow0 + r) * 128;
    #pragma unroll
    for (int dc = 0; dc < 4; dc++) qf[dc] = *(const bf16x8*)(qp + dc * 32 + g * 8);

    f32x4 o_acc[8] = {};
    float m_run[4], l_run[4];
    #pragma unroll
    for (int j = 0; j < 4; j++) { m_run[j] = -1e30f; l_run[j] = 0.f; }

    const float scale = 0.08838834764831845f;
    const int kv_end = qt * 64 + 64;

    for (int kv0 = 0; kv0 < kv_end; kv0 += 64) {
        __syncthreads();
        {
            int tr = tid >> 2;
            const bf16* src = Kb + ((long)hk * T + kv0 + tr) * 128;
            #pragma unroll
            for (int q4 = 0; q4 < 4; q4++) {
                int c = (tid & 3) * 4 + q4;
                bf16x8 v = *(const bf16x8*)(src + c * 8);
                *(bf16x8*)&Ks[tr][(c ^ (tr & 7)) * 8] = v;
            }
        }
        {
            int dd = tid >> 1;
            const bf16* src = Vt + ((long)hk * 128 + dd) * T + kv0;
            #pragma unroll
            for (int q4 = 0; q4 < 4; q4++) {
                int c = (tid & 1) * 4 + q4;
                bf16x8 v = *(const bf16x8*)(src + c * 8);
                *(bf16x8*)&Vs[dd][(c ^ (dd & 7)) * 8] = v;
            }
        }
        __syncthreads();

        f32x4 s[4] = {};
        #pragma unroll
        for (int n = 0; n < 4; n++) {
            int tr = n * 16 + r;
            #pragma unroll
            for (int dc = 0; dc < 4; dc++) {
                int c = (dc * 4 + g) ^ (tr & 7);
                bf16x8 kf = *(const bf16x8*)&Ks[tr][c * 8];
                s[n] = __builtin_amdgcn_mfma_f32_16x16x32_bf16(qf[dc], kf, s[n], 0, 0, 0);
            }
        }

        #pragma unroll
        for (int j = 0; j < 4; j++) {
            int qpos = qrow0 + g * 4 + j;
            float mx = m_run[j];
            #pragma unroll
            for (int n = 0; n < 4; n++) {
                int kpos = kv0 + n * 16 + r;
                float sv = s[n][j] * scale;
                sv = (kpos <= qpos) ? sv : -1e30f;
                s[n][j] = sv;
                mx = fmaxf(mx, sv);
            }
            #pragma unroll
            for (int mask = 1; mask < 16; mask <<= 1) mx = fmaxf(mx, __shfl_xor(mx, mask));
            float corr = __expf(m_run[j] - mx);
            l_run[j] *= corr;
            #pragma unroll
            for (int db = 0; db < 8; db++) o_acc[db][j] *= corr;
            float ls = 0.f;
            #pragma unroll
            for (int n = 0; n < 4; n++) {
                float p = __expf(s[n][j] - mx);
                s[n][j] = p;
                ls += p;
            }
            #pragma unroll
            for (int mask = 1; mask < 16; mask <<= 1) ls += __shfl_xor(ls, mask);
            l_run[j] += ls;
            m_run[j] = mx;
        }

        #pragma unroll
        for (int n = 0; n < 4; n++)
            #pragma unroll
            for (int j = 0; j < 4; j++)
                Ps[w][g * 4 + j][n * 16 + r] = (bf16)s[n][j];
        __syncthreads();

        bf16x8 pf[2];
        #pragma unroll
        for (int kc = 0; kc < 2; kc++)
            pf[kc] = *(const bf16x8*)&Ps[w][r][kc * 32 + g * 8];
        #pragma unroll
        for (int db = 0; db < 8; db++) {
            #pragma unroll
            for (int kc = 0; kc < 2; kc++) {
                int dd = db * 16 + r;
                int c = (kc * 4 + g) ^ (dd & 7);
                bf16x8 vf = *(const bf16x8*)&Vs[dd][c * 8];
                o_acc[db] = __builtin_amdgcn_mfma_f32_16x16x32_bf16(pf[kc], vf, o_acc[db], 0, 0, 0);
            }
        }
    }

    #pragma unroll
    for (int db = 0; db < 8; db++) {
        #pragma unroll
        for (int j = 0; j < 4; j++) {
            int t = qrow0 + g * 4 + j;
            float v = o_acc[db][j] / l_run[j];
            O[(long)t * 4096 + h * 128 + db * 16 + r] = (bf16)v;
        }
    }
}

// ---------------------------------------------------------------------------
extern "C" void kernel_launch(void* const* d_in, const int* in_sizes, int n_in,
                              void* d_out, int out_size, void* d_ws, size_t ws_size,
                              hipStream_t stream)
{
    const float* X   = (const float*)d_in[0];
    const float* LN1 = (const float*)d_in[1];
    const float* LN2 = (const float*)d_in[2];
    const float* qUs = (const float*)d_in[3];
    const float* qV  = (const float*)d_in[4];
    const float* kUs = (const float*)d_in[5];
    const float* kV  = (const float*)d_in[6];
    const float* vUs = (const float*)d_in[7];
    const float* vV  = (const float*)d_in[8];
    const float* oUs = (const float*)d_in[9];
    const float* oV  = (const float*)d_in[10];
    const float* gUs = (const float*)d_in[11];
    const float* gV  = (const float*)d_in[12];
    const float* uUs = (const float*)d_in[13];
    const float* uV  = (const float*)d_in[14];
    const float* dUs = (const float*)d_in[15];
    const float* dV  = (const float*)d_in[16];
    float* OUT = (float*)d_out;

    char* w = (char*)d_ws;
    bf16*  h1   = (bf16*)(w + 0);          // [1024,4096]
    bf16*  xrq  = (bf16*)(w + 8388608);    // [1024,2048]
    bf16*  xrk  = (bf16*)(w + 12582912);   // [1024,512]
    bf16*  xrv  = (bf16*)(w + 13631488);   // [1024,512]
    bf16*  qb   = (bf16*)(w + 14680064);   // [32,1024,128]
    bf16*  kb   = (bf16*)(w + 23068672);   // [8,1024,128]
    bf16*  vt   = (bf16*)(w + 25165824);   // [8,128,1024]
    float* cs   = (float*)(w + 27262976);  // [1024,64]
    float* sn   = (float*)(w + 27525120);  // [1024,64]
    bf16*  att  = (bf16*)(w + 27787264);   // [1024,4096]
    bf16*  r1   = (bf16*)(w + 36175872);   // [1024,1024]
    bf16*  h2   = (bf16*)(w + 0);
    bf16*  gr   = (bf16*)(w + 8388608);
    bf16*  ur   = (bf16*)(w + 10485760);
    bf16*  hmid = (bf16*)(w + 12582912);   // [1024,14336]
    bf16*  dr   = (bf16*)(w + 41943040);   // [1024,1024]
    const size_t ARENA  = 44040192;
    const size_t PARTSZ = 33554432;
    float* part = (float*)(w + ARENA);
    const bool med = ws_size >= ARENA + PARTSZ;

    dim3 blk(256);

    if (med) {
        rmsnorm_k<<<1024, blk, 0, stream>>>(X, LN1, h1);
        // xr_q: K=4096 split 4 -> 512 blocks
        gemm3f<EPI_PART><<<dim3(128,1,4), blk, 0, stream>>>(h1,4096,0, qV,4096,0,nullptr, part,2048,2097152, nullptr, 1024,4, 8);
        reduce_k<<<2048, blk, 0, stream>>>(part, 2097152, 4, xrq);
        // xr_k + xr_v batched (share A=h1), split 4 -> 256 blocks
        gemm3f<EPI_PART><<<dim3(32,1,8), blk, 0, stream>>>(h1,4096,0, kV,4096,0,vV, part,512,524288, nullptr, 1024,4, 8);
        reduce_k<<<512, blk, 0, stream>>>(part,             524288, 4, xrk);
        reduce_k<<<512, blk, 0, stream>>>(part + 4L*524288, 524288, 4, xrv);

        gemm3f<EPI_BF16 ><<<dim3(8,1,32), blk, 0, stream>>>(xrq,2048,64, qUs,64,8192,nullptr, qb,128,131072, nullptr, 64,1, 8);
        gemm3f<EPI_BF16 ><<<dim3(8,1, 8), blk, 0, stream>>>(xrk, 512,64, kUs,64,8192,nullptr, kb,128,131072, nullptr, 64,1, 8);
        gemm3f<EPI_BF16T><<<dim3(8,1, 8), blk, 0, stream>>>(xrv, 512,64, vUs,64,8192,nullptr, vt,1024,131072, nullptr, 64,1, 8);
        rope_table_k<<<256, blk, 0, stream>>>(cs, sn);
        rope_k<<<8192, blk, 0, stream>>>(qb, cs, sn);
        rope_k<<<2048, blk, 0, stream>>>(kb, cs, sn);
        attn_k<<<dim3(16,32), blk, 0, stream>>>(qb, kb, vt, att);

        gemm3f<EPI_PART><<<dim3(64,1,4), blk, 0, stream>>>(att,4096,0, oV,4096,0,nullptr, part,1024,1048576, nullptr, 1024,4, 8);
        reduce_k<<<1024, blk, 0, stream>>>(part, 1048576, 4, r1);
        gemm3f<EPI_F32ADD><<<dim3(256,1,1), blk, 0, stream>>>(r1,1024,0, oUs,1024,0,nullptr, OUT,4096,0, X, 1024,1, 8);

        rmsnorm_k<<<1024, blk, 0, stream>>>(OUT, LN2, h2);
        gemm3f<EPI_PART><<<dim3(64,1,8), blk, 0, stream>>>(h2,4096,0, gV,4096,0,uV, part,1024,1048576, nullptr, 1024,4, 8);
        reduce_k<<<1024, blk, 0, stream>>>(part,              1048576, 4, gr);
        reduce_k<<<1024, blk, 0, stream>>>(part + 4L*1048576, 1048576, 4, ur);
        gemmr<EPI_SILU1><<<dim3(896,1,1), blk, 0, stream>>>(gr,1024,0, gUs,1024,0,nullptr, hmid,14336,0, nullptr, 1024,1, 8);
        gemmr<EPI_MUL  ><<<dim3(896,1,1), blk, 0, stream>>>(ur,1024,0, uUs,1024,0,nullptr, hmid,14336,0, nullptr, 1024,1, 8);
        gemmr<EPI_PART><<<dim3(64,1,7), blk, 0, stream>>>(hmid,14336,0, dV,14336,0,nullptr, part,1024,1048576, nullptr, 2048,7, 8);
        reduce_k<<<1024, blk, 0, stream>>>(part, 1048576, 7, dr);
        gemm3f<EPI_F32ADD><<<dim3(256,1,1), blk, 0, stream>>>(dr,1024,0, dUs,1024,0,nullptr, OUT,4096,0, OUT, 1024,1, 8);
        return;
    }

    // ---------------- fallback: gemm2 (fp32-B dbuf) path ----------------
    rmsnorm_k<<<1024, blk, 0, stream>>>(X, LN1, h1);
    gemm2<EPI_BF16><<<dim3(8,16,1), blk, 0, stream>>>(h1,4096,0, qV,4096,0,nullptr, xrq,2048,0, nullptr, 4096, 1);
    gemm2<EPI_BF16><<<dim3(8, 4,1), blk, 0, stream>>>(h1,4096,0, kV,4096,0,nullptr, xrk, 512,0, nullptr, 4096, 1);
    gemm2<EPI_BF16><<<dim3(8, 4,1), blk, 0, stream>>>(h1,4096,0, vV,4096,0,nullptr, xrv, 512,0, nullptr, 4096, 1);
    gemm2<EPI_BF16 ><<<dim3(8,1,32), blk, 0, stream>>>(xrq,2048,64, qUs,64,8192,nullptr, qb,128,131072, nullptr, 64, 1);
    gemm2<EPI_BF16 ><<<dim3(8,1, 8), blk, 0, stream>>>(xrk, 512,64, kUs,64,8192,nullptr, kb,128,131072, nullptr, 64, 1);
    gemm2<EPI_BF16T><<<dim3(8,1, 8), blk, 0, stream>>>(xrv, 512,64, vUs,64,8192,nullptr, vt,1024,131072, nullptr, 64, 1);
    rope_table_k<<<256, blk, 0, stream>>>(cs, sn);
    rope_k<<<8192, blk, 0, stream>>>(qb, cs, sn);
    rope_k<<<2048, blk, 0, stream>>>(kb, cs, sn);
    attn_k<<<dim3(16,32), blk, 0, stream>>>(qb, kb, vt, att);
    gemm2<EPI_BF16><<<dim3(8,8,1), blk, 0, stream>>>(att,4096,0, oV,4096,0,nullptr, r1,1024,0, nullptr, 4096, 1);
    gemm2<EPI_F32ADD><<<dim3(8,32,1), blk, 0, stream>>>(r1,1024,0, oUs,1024,0,nullptr, OUT,4096,0, X, 1024, 1);
    rmsnorm_k<<<1024, blk, 0, stream>>>(OUT, LN2, h2);
    gemm2<EPI_BF16><<<dim3(8,8,1), blk, 0, stream>>>(h2,4096,0, gV,4096,0,nullptr, gr,1024,0, nullptr, 4096, 1);
    gemm2<EPI_BF16><<<dim3(8,8,1), blk, 0, stream>>>(h2,4096,0, uV,4096,0,nullptr, ur,1024,0, nullptr, 4096, 1);
    gemm2<EPI_SILU1><<<dim3(8,112,1), blk, 0, stream>>>(gr,1024,0, gUs,1024,0,nullptr, hmid,14336,0, nullptr, 1024, 1);
    gemm2<EPI_MUL  ><<<dim3(8,112,1), blk, 0, stream>>>(ur,1024,0, uUs,1024,0,nullptr, hmid,14336,0, nullptr, 1024, 1);
    gemm2<EPI_BF16><<<dim3(8,8,1), blk, 0, stream>>>(hmid,14336,0, dV,14336,0,nullptr, dr,1024,0, nullptr, 14336, 1);
    gemm2<EPI_F32ADD><<<dim3(8,32,1), blk, 0, stream>>>(dr,1024,0, dUs,1024,0,nullptr, OUT,4096,0, OUT, 1024, 1);
}

// Round 10
// 545.289 us; speedup vs baseline: 1.5854x; 1.5854x over previous
//
#include <hip/hip_runtime.h>
#include <math.h>

// ---------------------------------------------------------------------------
// FlashSVD LLaMA block, round 10: exact round-6 base (proven 527us) + one
// targeted change: the three heavy MLP GEMMs (SILU, MUL, dV; 3x85us) use
// bf16-B gemm3b (m97 regime: 32KB LDS, 5 blk/CU — proven in r5), fed by a
// single fully-parallel 3-tensor fp32->bf16 cvt (~45us, vs r5's 120us
// serialized 14-tensor cvt). Per-step staged bytes 48->32KB, occupancy 3->5.
// ---------------------------------------------------------------------------

typedef __bf16 bf16;
typedef __bf16 bf16x8 __attribute__((ext_vector_type(8)));
typedef __bf16 bf16x4 __attribute__((ext_vector_type(4)));
typedef float  f32x4  __attribute__((ext_vector_type(4)));

#define EPI_BF16   0
#define EPI_BF16T  1   // transposed bf16 store (V in [d][t] layout)
#define EPI_F32ADD 2   // fp32 store with residual add
#define EPI_SILU1  3   // store silu(acc) bf16
#define EPI_MUL    4   // RMW: C *= acc (bf16)
#define EPI_PART   5   // fp32 partial plane store (split-K)

__device__ __forceinline__ void gld16(const void* g, void* l) {
    __builtin_amdgcn_global_load_lds(
        (const __attribute__((address_space(1))) unsigned int*)g,
        (__attribute__((address_space(3))) unsigned int*)l, 16, 0, 0);
}

// ---------------------------------------------------------------------------
// gemm3b: A bf16 [M,K], B bf16 [N,K], 128x128 tile, BK=64, 4 waves (2x2),
// single-buffered 32KB LDS (m97 regime, ~5 blk/CU), 2 barriers/K-step, both
// operands via global_load_lds with pre-swizzled source (chunk ^= row&7).
// Grid: dim3(nwg,1,z); XCD-bijective remap; bm=id%gx, bn=id/gx.
// ---------------------------------------------------------------------------
template<int EPI>
__global__ __launch_bounds__(256)
void gemm3b(const bf16* __restrict__ A, int lda, long sA,
            const bf16* __restrict__ B, int ldb, long sB, const bf16* __restrict__ B2,
            void* __restrict__ Cv, int ldc, long sC,
            const float* __restrict__ R, int Kc, int nsplit, int gx)
{
    __shared__ __align__(16) bf16 As[128 * 64];   // 16 KB
    __shared__ __align__(16) bf16 Bs[128 * 64];   // 16 KB

    const int tid = threadIdx.x, lane = tid & 63, w = tid >> 6;
    const int wr = w >> 1, wc = w & 1;

    int id = blockIdx.x;
    {   // bijective XCD remap (m204)
        const int nwg = gridDim.x;
        int q = nwg >> 3, rr = nwg & 7;
        int xcd = id & 7, off = id >> 3;
        id = (xcd < rr ? xcd * (q + 1) : rr * (q + 1) + (xcd - rr) * q) + off;
    }
    const int bm = id % gx, bn = id / gx, bz = blockIdx.z;
    const int ks = bz % nsplit, zb = bz / nsplit;

    const bf16* Bp = (B2 != nullptr && zb != 0) ? B2 : B;
    const bf16* Ab = A  + (long)zb * sA + (long)(bm * 128) * lda + (long)ks * Kc;
    const bf16* Bb = Bp + (long)zb * sB + (long)(bn * 128) * ldb + (long)ks * Kc;

    const int g = lane >> 4, r = lane & 15;
    f32x4 acc[4][4] = {};
    const int nt = Kc >> 6;

    for (int t = 0; t < nt; t++) {
        if (t) __syncthreads();
        const bf16* At = Ab + t * 64;
        const bf16* Bt = Bb + t * 64;
        #pragma unroll
        for (int i = 0; i < 4; i++) {        // 1024 chunks each, 4 instr/wave
            int cb = w * 256 + i * 64, ci = cb + lane;
            int row = ci >> 3, col = ((ci & 7) ^ (row & 7)) * 8;
            gld16(At + (long)row * lda + col, &As[cb * 8]);
            gld16(Bt + (long)row * ldb + col, &Bs[cb * 8]);
        }
        __syncthreads();
        #pragma unroll
        for (int kk = 0; kk < 2; kk++) {
            bf16x8 af[4], bfr[4];
            #pragma unroll
            for (int m = 0; m < 4; m++) {
                int row = wr * 64 + m * 16 + r;
                af[m] = *(const bf16x8*)&As[row * 64 + (((kk * 4 + g) ^ (row & 7)) * 8)];
            }
            #pragma unroll
            for (int n = 0; n < 4; n++) {
                int row = wc * 64 + n * 16 + r;
                bfr[n] = *(const bf16x8*)&Bs[row * 64 + (((kk * 4 + g) ^ (row & 7)) * 8)];
            }
            #pragma unroll
            for (int m = 0; m < 4; m++)
                #pragma unroll
                for (int n = 0; n < 4; n++)
                    acc[m][n] = __builtin_amdgcn_mfma_f32_16x16x32_bf16(af[m], bfr[n], acc[m][n], 0, 0, 0);
        }
    }

    // epilogue: C layout col = lane&15, row = (lane>>4)*4 + j
    #pragma unroll
    for (int m = 0; m < 4; m++) {
        #pragma unroll
        for (int n = 0; n < 4; n++) {
            const int row0 = bm * 128 + wr * 64 + m * 16 + g * 4;
            const int col  = bn * 128 + wc * 64 + n * 16 + r;
            #pragma unroll
            for (int j = 0; j < 4; j++) {
                float v = acc[m][n][j];
                long row = row0 + j;
                if constexpr (EPI == EPI_BF16) {
                    ((bf16*)Cv)[(long)zb * sC + row * (long)ldc + col] = (bf16)v;
                } else if constexpr (EPI == EPI_BF16T) {
                    ((bf16*)Cv)[(long)zb * sC + (long)col * ldc + row] = (bf16)v;
                } else if constexpr (EPI == EPI_F32ADD) {
                    long idx = row * (long)ldc + col;
                    ((float*)Cv)[idx] = v + R[idx];
                } else if constexpr (EPI == EPI_PART) {
                    ((float*)Cv)[(long)bz * sC + row * (long)ldc + col] = v;
                } else if constexpr (EPI == EPI_SILU1) {
                    ((bf16*)Cv)[row * (long)ldc + col] = (bf16)(v / (1.f + __expf(-v)));
                } else { // EPI_MUL
                    bf16* p = &((bf16*)Cv)[row * (long)ldc + col];
                    *p = (bf16)((float)*p * v);
                }
            }
        }
    }
}

// ---------------------------------------------------------------------------
// gemm3f (round-6, proven): fp32-B direct staging, 48KB LDS, 2 barriers/step.
// ---------------------------------------------------------------------------
template<int EPI>
__global__ __launch_bounds__(256)
void gemm3f(const bf16* __restrict__ A, int lda, long sA,
            const float* __restrict__ B, int ldb, long sB, const float* __restrict__ B2,
            void* __restrict__ Cv, int ldc, long sC,
            const float* __restrict__ R, int Kc, int nsplit, int gx)
{
    __shared__ __align__(16) bf16  As[128 * 64];   // 16 KB
    __shared__ __align__(16) float Bs[128 * 64];   // 32 KB

    const int tid = threadIdx.x, lane = tid & 63, w = tid >> 6;
    const int wr = w >> 1, wc = w & 1;

    int id = blockIdx.x;
    {
        const int nwg = gridDim.x;
        int q = nwg >> 3, rr = nwg & 7;
        int xcd = id & 7, off = id >> 3;
        id = (xcd < rr ? xcd * (q + 1) : rr * (q + 1) + (xcd - rr) * q) + off;
    }
    const int bm = id % gx, bn = id / gx, bz = blockIdx.z;
    const int ks = bz % nsplit, zb = bz / nsplit;

    const float* Bp = (B2 != nullptr && zb != 0) ? B2 : B;
    const bf16*  Ab = A  + (long)zb * sA + (long)(bm * 128) * lda + (long)ks * Kc;
    const float* Bb = Bp + (long)zb * sB + (long)(bn * 128) * ldb + (long)ks * Kc;

    const int g = lane >> 4, r = lane & 15;
    f32x4 acc[4][4] = {};
    const int nt = Kc >> 6;

    for (int t = 0; t < nt; t++) {
        if (t) __syncthreads();
        const bf16*  At = Ab + t * 64;
        const float* Bt = Bb + t * 64;
        #pragma unroll
        for (int i = 0; i < 4; i++) {
            int cb = w * 256 + i * 64, ci = cb + lane;
            int row = ci >> 3, col = ((ci & 7) ^ (row & 7)) * 8;
            gld16(At + (long)row * lda + col, &As[cb * 8]);
        }
        #pragma unroll
        for (int i = 0; i < 8; i++) {
            int cb = w * 512 + i * 64, ci = cb + lane;
            int row = ci >> 4, col = ((ci & 15) ^ (row & 15)) * 4;
            gld16(Bt + (long)row * ldb + col, &Bs[cb * 4]);
        }
        __syncthreads();
        #pragma unroll
        for (int kk = 0; kk < 2; kk++) {
            bf16x8 af[4], bfr[4];
            #pragma unroll
            for (int m = 0; m < 4; m++) {
                int row = wr * 64 + m * 16 + r;
                af[m] = *(const bf16x8*)&As[row * 64 + (((kk * 4 + g) ^ (row & 7)) * 8)];
            }
            #pragma unroll
            for (int n = 0; n < 4; n++) {
                int row = wc * 64 + n * 16 + r;
                int c0 = kk * 8 + g * 2;
                f32x4 lo = *(const f32x4*)&Bs[row * 64 + (((c0    ) ^ (row & 15)) * 4)];
                f32x4 hi = *(const f32x4*)&Bs[row * 64 + (((c0 + 1) ^ (row & 15)) * 4)];
                bfr[n] = bf16x8{(bf16)lo[0], (bf16)lo[1], (bf16)lo[2], (bf16)lo[3],
                                (bf16)hi[0], (bf16)hi[1], (bf16)hi[2], (bf16)hi[3]};
            }
            #pragma unroll
            for (int m = 0; m < 4; m++)
                #pragma unroll
                for (int n = 0; n < 4; n++)
                    acc[m][n] = __builtin_amdgcn_mfma_f32_16x16x32_bf16(af[m], bfr[n], acc[m][n], 0, 0, 0);
        }
    }

    #pragma unroll
    for (int m = 0; m < 4; m++) {
        #pragma unroll
        for (int n = 0; n < 4; n++) {
            const int row0 = bm * 128 + wr * 64 + m * 16 + g * 4;
            const int col  = bn * 128 + wc * 64 + n * 16 + r;
            #pragma unroll
            for (int j = 0; j < 4; j++) {
                float v = acc[m][n][j];
                long row = row0 + j;
                if constexpr (EPI == EPI_BF16) {
                    ((bf16*)Cv)[(long)zb * sC + row * (long)ldc + col] = (bf16)v;
                } else if constexpr (EPI == EPI_BF16T) {
                    ((bf16*)Cv)[(long)zb * sC + (long)col * ldc + row] = (bf16)v;
                } else if constexpr (EPI == EPI_F32ADD) {
                    long idx = row * (long)ldc + col;
                    ((float*)Cv)[idx] = v + R[idx];
                } else if constexpr (EPI == EPI_PART) {
                    ((float*)Cv)[(long)bz * sC + row * (long)ldc + col] = v;
                } else if constexpr (EPI == EPI_SILU1) {
                    ((bf16*)Cv)[row * (long)ldc + col] = (bf16)(v / (1.f + __expf(-v)));
                } else {
                    bf16* p = &((bf16*)Cv)[row * (long)ldc + col];
                    *p = (bf16)((float)*p * v);
                }
            }
        }
    }
}

// ---------------------------------------------------------------------------
// cvt3_k: parallel fp32->bf16 for three equal-size tensors (z selects tensor).
// ---------------------------------------------------------------------------
__global__ __launch_bounds__(256)
void cvt3_k(const float* __restrict__ s0, const float* __restrict__ s1,
            const float* __restrict__ s2,
            bf16* __restrict__ d0, bf16* __restrict__ d1, bf16* __restrict__ d2,
            long n)
{
    const float* s = blockIdx.z == 0 ? s0 : (blockIdx.z == 1 ? s1 : s2);
    bf16*        d = blockIdx.z == 0 ? d0 : (blockIdx.z == 1 ? d1 : d2);
    const long n8 = n >> 3;
    const long stride = (long)gridDim.x * 256;
    for (long i = (long)blockIdx.x * 256 + threadIdx.x; i < n8; i += stride) {
        const float4* sp = (const float4*)s + i * 2;
        float4 f0 = sp[0], f1 = sp[1];
        bf16x8 h = {(bf16)f0.x,(bf16)f0.y,(bf16)f0.z,(bf16)f0.w,
                    (bf16)f1.x,(bf16)f1.y,(bf16)f1.z,(bf16)f1.w};
        *(bf16x8*)(d + i * 8) = h;
    }
}

// ---------------------------------------------------------------------------
// gemm2 (fallback for small workspace): fp32 B converted in staging, dbuf.
// ---------------------------------------------------------------------------
template<int EPI>
__global__ __launch_bounds__(256)
void gemm2(const bf16* __restrict__ A, int lda, long sA,
           const float* __restrict__ B, int ldb, long sB, const float* __restrict__ B2,
           void* __restrict__ Cv, int ldc, long sC,
           const float* __restrict__ R, int Kc, int nsplit)
{
    __shared__ __align__(16) bf16 As[2][128 * 64];
    __shared__ __align__(16) bf16 Bs[2][128 * 64];

    const int tid = threadIdx.x, lane = tid & 63, w = tid >> 6;
    const int wr = w >> 1, wc = w & 1;
    const int bm = blockIdx.x, bn = blockIdx.y, bz = blockIdx.z;
    const int ks = bz % nsplit, zb = bz / nsplit;

    const float* Bp = (B2 != nullptr && zb != 0) ? B2 : B;
    const bf16*  Ab = A  + (long)zb * sA + (long)(bm * 128) * lda + (long)ks * Kc;
    const float* Bb = Bp + (long)zb * sB + (long)(bn * 128) * ldb + (long)ks * Kc;

    const int g = lane >> 4, r = lane & 15;
    f32x4 acc[4][4] = {};
    const int nt = Kc >> 6;
    int cur = 0;

    {
        #pragma unroll
        for (int i = 0; i < 4; i++) {
            int cb = i * 256 + w * 64, ci = cb + lane;
            int arow = ci >> 3, acol = ((ci & 7) ^ (arow & 7)) * 8;
            gld16(Ab + (long)arow * lda + acol, &As[0][cb * 8]);
        }
        float4 fb[8];
        #pragma unroll
        for (int i = 0; i < 8; i++) {
            int p = i * 256 + tid;
            fb[i] = *(const float4*)(Bb + (long)(p >> 4) * ldb + (p & 15) * 4);
        }
        #pragma unroll
        for (int i = 0; i < 8; i++) {
            int p = i * 256 + tid, brow = p >> 4, c4 = p & 15;
            bf16x4 h = {(bf16)fb[i].x, (bf16)fb[i].y, (bf16)fb[i].z, (bf16)fb[i].w};
            *(bf16x4*)&Bs[0][brow * 64 + (((c4 >> 1) ^ (brow & 7)) * 8) + (c4 & 1) * 4] = h;
        }
    }
    __syncthreads();

    for (int t = 0; t < nt; t++) {
        float4 fb[8];
        if (t + 1 < nt) {
            const bf16* An = Ab + (t + 1) * 64;
            #pragma unroll
            for (int i = 0; i < 4; i++) {
                int cb = i * 256 + w * 64, ci = cb + lane;
                int arow = ci >> 3, acol = ((ci & 7) ^ (arow & 7)) * 8;
                gld16(An + (long)arow * lda + acol, &As[cur ^ 1][cb * 8]);
            }
            const float* Bn = Bb + (t + 1) * 64;
            #pragma unroll
            for (int i = 0; i < 8; i++) {
                int p = i * 256 + tid;
                fb[i] = *(const float4*)(Bn + (long)(p >> 4) * ldb + (p & 15) * 4);
            }
        }
        #pragma unroll
        for (int kk = 0; kk < 2; kk++) {
            bf16x8 af[4], bfr[4];
            #pragma unroll
            for (int m = 0; m < 4; m++) {
                int row = wr * 64 + m * 16 + r;
                af[m] = *(const bf16x8*)&As[cur][row * 64 + (((kk * 4 + g) ^ (row & 7)) * 8)];
            }
            #pragma unroll
            for (int n = 0; n < 4; n++) {
                int row = wc * 64 + n * 16 + r;
                bfr[n] = *(const bf16x8*)&Bs[cur][row * 64 + (((kk * 4 + g) ^ (row & 7)) * 8)];
            }
            #pragma unroll
            for (int m = 0; m < 4; m++)
                #pragma unroll
                for (int n = 0; n < 4; n++)
                    acc[m][n] = __builtin_amdgcn_mfma_f32_16x16x32_bf16(af[m], bfr[n], acc[m][n], 0, 0, 0);
        }
        if (t + 1 < nt) {
            #pragma unroll
            for (int i = 0; i < 8; i++) {
                int p = i * 256 + tid, brow = p >> 4, c4 = p & 15;
                bf16x4 h = {(bf16)fb[i].x, (bf16)fb[i].y, (bf16)fb[i].z, (bf16)fb[i].w};
                *(bf16x4*)&Bs[cur ^ 1][brow * 64 + (((c4 >> 1) ^ (brow & 7)) * 8) + (c4 & 1) * 4] = h;
            }
            __syncthreads();
            cur ^= 1;
        }
    }

    #pragma unroll
    for (int m = 0; m < 4; m++) {
        #pragma unroll
        for (int n = 0; n < 4; n++) {
            const int row0 = bm * 128 + wr * 64 + m * 16 + g * 4;
            const int col  = bn * 128 + wc * 64 + n * 16 + r;
            #pragma unroll
            for (int j = 0; j < 4; j++) {
                float v = acc[m][n][j];
                long row = row0 + j;
                if constexpr (EPI == EPI_BF16) {
                    ((bf16*)Cv)[(long)zb * sC + row * (long)ldc + col] = (bf16)v;
                } else if constexpr (EPI == EPI_BF16T) {
                    ((bf16*)Cv)[(long)zb * sC + (long)col * ldc + row] = (bf16)v;
                } else if constexpr (EPI == EPI_F32ADD) {
                    long idx = row * (long)ldc + col;
                    ((float*)Cv)[idx] = v + R[idx];
                } else if constexpr (EPI == EPI_PART) {
                    ((float*)Cv)[(long)bz * sC + row * (long)ldc + col] = v;
                } else if constexpr (EPI == EPI_SILU1) {
                    ((bf16*)Cv)[row * (long)ldc + col] = (bf16)(v / (1.f + __expf(-v)));
                } else {
                    bf16* p = &((bf16*)Cv)[row * (long)ldc + col];
                    *p = (bf16)((float)*p * v);
                }
            }
        }
    }
}

// ---------------------------------------------------------------------------
__global__ __launch_bounds__(256)
void reduce_k(const float* __restrict__ part, long pe, int np, bf16* __restrict__ out)
{
    long i = ((long)blockIdx.x * 256 + threadIdx.x) * 4;
    float4 s = *(const float4*)&part[i];
    for (int p = 1; p < np; p++) {
        float4 v = *(const float4*)&part[(long)p * pe + i];
        s.x += v.x; s.y += v.y; s.z += v.z; s.w += v.w;
    }
    bf16x4 o = {(bf16)s.x, (bf16)s.y, (bf16)s.z, (bf16)s.w};
    *(bf16x4*)&out[i] = o;
}

__global__ __launch_bounds__(256)
void rmsnorm_k(const float* __restrict__ x, const float* __restrict__ w,
               bf16* __restrict__ out)
{
    const int D = 4096;
    const long row = blockIdx.x;
    const float* xr = x + row * D;
    float4 v[4];
    float ss = 0.f;
    #pragma unroll
    for (int k = 0; k < 4; k++) {
        v[k] = *(const float4*)&xr[threadIdx.x * 4 + k * 1024];
        ss += v[k].x * v[k].x + v[k].y * v[k].y + v[k].z * v[k].z + v[k].w * v[k].w;
    }
    #pragma unroll
    for (int o = 32; o > 0; o >>= 1) ss += __shfl_down(ss, o);
    __shared__ float red[4];
    if ((threadIdx.x & 63) == 0) red[threadIdx.x >> 6] = ss;
    __syncthreads();
    float rs = rsqrtf((red[0] + red[1] + red[2] + red[3]) / D + 1e-5f);
    #pragma unroll
    for (int k = 0; k < 4; k++) {
        int i = threadIdx.x * 4 + k * 1024;
        float4 wv = *(const float4*)&w[i];
        bf16x4 o4 = {(bf16)(v[k].x * rs * wv.x), (bf16)(v[k].y * rs * wv.y),
                     (bf16)(v[k].z * rs * wv.z), (bf16)(v[k].w * rs * wv.w)};
        *(bf16x4*)&out[row * D + i] = o4;
    }
}

__global__ __launch_bounds__(256)
void rope_table_k(float* cs, float* sn)
{
    int idx = blockIdx.x * blockDim.x + threadIdx.x;  // 1024*64
    int t = idx >> 6, i = idx & 63;
    float inv = powf(10000.0f, -(2.0f * i) / 128.0f);
    float a = (float)t * inv;
    cs[idx] = cosf(a);
    sn[idx] = sinf(a);
}

__global__ __launch_bounds__(256)
void rope_k(bf16* qk, const float* __restrict__ cs, const float* __restrict__ sn)
{
    long idx = (long)blockIdx.x * blockDim.x + threadIdx.x;
    int d = idx & 63;
    long ht = idx >> 6;
    int t = (int)(ht & 1023);
    bf16* p = qk + ht * 128;
    float x1 = (float)p[d], x2 = (float)p[d + 64];
    int i1 = d >> 1;
    float c1 = cs[t * 64 + i1],      s1 = sn[t * 64 + i1];
    float c2 = cs[t * 64 + 32 + i1], s2 = sn[t * 64 + 32 + i1];
    p[d]      = (bf16)(x1 * c1 - x2 * s1);
    p[d + 64] = (bf16)(x2 * c2 + x1 * s2);
}

// ---------------------------------------------------------------------------
// Flash attention (causal, GQA 4:1), 4 waves x 16 q-rows, KV tile 64.
// ---------------------------------------------------------------------------
__global__ __launch_bounds__(256)
void attn_k(const bf16* __restrict__ Q,   // [32][1024][128]
            const bf16* __restrict__ Kb,  // [8][1024][128]
            const bf16* __restrict__ Vt,  // [8][128][1024]
            bf16* __restrict__ O)         // [1024][4096]
{
    const int T = 1024;
    __shared__ __align__(16) bf16 Ks[64][128];
    __shared__ __align__(16) bf16 Vs[128][64];
    __shared__ __align__(16) bf16 Ps[4][16][72];

    const int qt = blockIdx.x, h = blockIdx.y, hk = h >> 2;
    const int tid = threadIdx.x, lane = tid & 63, w = tid >> 6;
    const int g = lane >> 4, r = lane & 15;
    const int qrow0 = qt * 64 + w * 16;

    bf16x8 qf[4];
    const bf16* qp = Q + ((long)h * T + qrow0 + r) * 128;
    #pragma unroll
    for (int dc = 0; dc < 4; dc++) qf[dc] = *(const bf16x8*)(qp + dc * 32 + g * 8);

    f32x4 o_acc[8] = {};
    float m_run[4], l_run[4];
    #pragma unroll
    for (int j = 0; j < 4; j++) { m_run[j] = -1e30f; l_run[j] = 0.f; }

    const float scale = 0.08838834764831845f;
    const int kv_end = qt * 64 + 64;

    for (int kv0 = 0; kv0 < kv_end; kv0 += 64) {
        __syncthreads();
        {
            int tr = tid >> 2;
            const bf16* src = Kb + ((long)hk * T + kv0 + tr) * 128;
            #pragma unroll
            for (int q4 = 0; q4 < 4; q4++) {
                int c = (tid & 3) * 4 + q4;
                bf16x8 v = *(const bf16x8*)(src + c * 8);
                *(bf16x8*)&Ks[tr][(c ^ (tr & 7)) * 8] = v;
            }
        }
        {
            int dd = tid >> 1;
            const bf16* src = Vt + ((long)hk * 128 + dd) * T + kv0;
            #pragma unroll
            for (int q4 = 0; q4 < 4; q4++) {
                int c = (tid & 1) * 4 + q4;
                bf16x8 v = *(const bf16x8*)(src + c * 8);
                *(bf16x8*)&Vs[dd][(c ^ (dd & 7)) * 8] = v;
            }
        }
        __syncthreads();

        f32x4 s[4] = {};
        #pragma unroll
        for (int n = 0; n < 4; n++) {
            int tr = n * 16 + r;
            #pragma unroll
            for (int dc = 0; dc < 4; dc++) {
                int c = (dc * 4 + g) ^ (tr & 7);
                bf16x8 kf = *(const bf16x8*)&Ks[tr][c * 8];
                s[n] = __builtin_amdgcn_mfma_f32_16x16x32_bf16(qf[dc], kf, s[n], 0, 0, 0);
            }
        }

        #pragma unroll
        for (int j = 0; j < 4; j++) {
            int qpos = qrow0 + g * 4 + j;
            float mx = m_run[j];
            #pragma unroll
            for (int n = 0; n < 4; n++) {
                int kpos = kv0 + n * 16 + r;
                float sv = s[n][j] * scale;
                sv = (kpos <= qpos) ? sv : -1e30f;
                s[n][j] = sv;
                mx = fmaxf(mx, sv);
            }
            #pragma unroll
            for (int mask = 1; mask < 16; mask <<= 1) mx = fmaxf(mx, __shfl_xor(mx, mask));
            float corr = __expf(m_run[j] - mx);
            l_run[j] *= corr;
            #pragma unroll
            for (int db = 0; db < 8; db++) o_acc[db][j] *= corr;
            float ls = 0.f;
            #pragma unroll
            for (int n = 0; n < 4; n++) {
                float p = __expf(s[n][j] - mx);
                s[n][j] = p;
                ls += p;
            }
            #pragma unroll
            for (int mask = 1; mask < 16; mask <<= 1) ls += __shfl_xor(ls, mask);
            l_run[j] += ls;
            m_run[j] = mx;
        }

        #pragma unroll
        for (int n = 0; n < 4; n++)
            #pragma unroll
            for (int j = 0; j < 4; j++)
                Ps[w][g * 4 + j][n * 16 + r] = (bf16)s[n][j];
        __syncthreads();

        bf16x8 pf[2];
        #pragma unroll
        for (int kc = 0; kc < 2; kc++)
            pf[kc] = *(const bf16x8*)&Ps[w][r][kc * 32 + g * 8];
        #pragma unroll
        for (int db = 0; db < 8; db++) {
            #pragma unroll
            for (int kc = 0; kc < 2; kc++) {
                int dd = db * 16 + r;
                int c = (kc * 4 + g) ^ (dd & 7);
                bf16x8 vf = *(const bf16x8*)&Vs[dd][c * 8];
                o_acc[db] = __builtin_amdgcn_mfma_f32_16x16x32_bf16(pf[kc], vf, o_acc[db], 0, 0, 0);
            }
        }
    }

    #pragma unroll
    for (int db = 0; db < 8; db++) {
        #pragma unroll
        for (int j = 0; j < 4; j++) {
            int t = qrow0 + g * 4 + j;
            float v = o_acc[db][j] / l_run[j];
            O[(long)t * 4096 + h * 128 + db * 16 + r] = (bf16)v;
        }
    }
}

// ---------------------------------------------------------------------------
extern "C" void kernel_launch(void* const* d_in, const int* in_sizes, int n_in,
                              void* d_out, int out_size, void* d_ws, size_t ws_size,
                              hipStream_t stream)
{
    const float* X   = (const float*)d_in[0];
    const float* LN1 = (const float*)d_in[1];
    const float* LN2 = (const float*)d_in[2];
    const float* qUs = (const float*)d_in[3];
    const float* qV  = (const float*)d_in[4];
    const float* kUs = (const float*)d_in[5];
    const float* kV  = (const float*)d_in[6];
    const float* vUs = (const float*)d_in[7];
    const float* vV  = (const float*)d_in[8];
    const float* oUs = (const float*)d_in[9];
    const float* oV  = (const float*)d_in[10];
    const float* gUs = (const float*)d_in[11];
    const float* gV  = (const float*)d_in[12];
    const float* uUs = (const float*)d_in[13];
    const float* uV  = (const float*)d_in[14];
    const float* dUs = (const float*)d_in[15];
    const float* dV  = (const float*)d_in[16];
    float* OUT = (float*)d_out;

    char* w = (char*)d_ws;
    bf16*  h1   = (bf16*)(w + 0);          // [1024,4096]
    bf16*  xrq  = (bf16*)(w + 8388608);    // [1024,2048]
    bf16*  xrk  = (bf16*)(w + 12582912);   // [1024,512]
    bf16*  xrv  = (bf16*)(w + 13631488);   // [1024,512]
    bf16*  qb   = (bf16*)(w + 14680064);   // [32,1024,128]
    bf16*  kb   = (bf16*)(w + 23068672);   // [8,1024,128]
    bf16*  vt   = (bf16*)(w + 25165824);   // [8,128,1024]
    float* cs   = (float*)(w + 27262976);  // [1024,64]
    float* sn   = (float*)(w + 27525120);  // [1024,64]
    bf16*  att  = (bf16*)(w + 27787264);   // [1024,4096]
    bf16*  r1   = (bf16*)(w + 36175872);   // [1024,1024]
    bf16*  h2   = (bf16*)(w + 0);
    bf16*  gr   = (bf16*)(w + 8388608);
    bf16*  ur   = (bf16*)(w + 10485760);
    bf16*  hmid = (bf16*)(w + 12582912);   // [1024,14336]
    bf16*  dr   = (bf16*)(w + 41943040);   // [1024,1024]
    const size_t ARENA  = 44040192;
    const size_t PARTSZ = 33554432;
    float* part = (float*)(w + ARENA);
    // bf16 weight copies for the three heavy MLP GEMMs (after part arena)
    const long NW = 14680064;              // 14336*1024 elements each
    bf16* gUsb = (bf16*)(w + ARENA + PARTSZ);
    bf16* uUsb = gUsb + NW;
    bf16* dVb  = uUsb + NW;
    const bool med = ws_size >= ARENA + PARTSZ;
    const bool big = ws_size >= ARENA + PARTSZ + 3ul * NW * sizeof(bf16);

    dim3 blk(256);

    if (med) {
        if (big)
            cvt3_k<<<dim3(1024,1,3), blk, 0, stream>>>(gUs, uUs, dV, gUsb, uUsb, dVb, NW);

        rmsnorm_k<<<1024, blk, 0, stream>>>(X, LN1, h1);
        // xr_q: K=4096 split 4 -> 512 blocks
        gemm3f<EPI_PART><<<dim3(128,1,4), blk, 0, stream>>>(h1,4096,0, qV,4096,0,nullptr, part,2048,2097152, nullptr, 1024,4, 8);
        reduce_k<<<2048, blk, 0, stream>>>(part, 2097152, 4, xrq);
        // xr_k + xr_v batched (share A=h1), split 4 -> 256 blocks
        gemm3f<EPI_PART><<<dim3(32,1,8), blk, 0, stream>>>(h1,4096,0, kV,4096,0,vV, part,512,524288, nullptr, 1024,4, 8);
        reduce_k<<<512, blk, 0, stream>>>(part,             524288, 4, xrk);
        reduce_k<<<512, blk, 0, stream>>>(part + 4L*524288, 524288, 4, xrv);

        gemm3f<EPI_BF16 ><<<dim3(8,1,32), blk, 0, stream>>>(xrq,2048,64, qUs,64,8192,nullptr, qb,128,131072, nullptr, 64,1, 8);
        gemm3f<EPI_BF16 ><<<dim3(8,1, 8), blk, 0, stream>>>(xrk, 512,64, kUs,64,8192,nullptr, kb,128,131072, nullptr, 64,1, 8);
        gemm3f<EPI_BF16T><<<dim3(8,1, 8), blk, 0, stream>>>(xrv, 512,64, vUs,64,8192,nullptr, vt,1024,131072, nullptr, 64,1, 8);
        rope_table_k<<<256, blk, 0, stream>>>(cs, sn);
        rope_k<<<8192, blk, 0, stream>>>(qb, cs, sn);
        rope_k<<<2048, blk, 0, stream>>>(kb, cs, sn);
        attn_k<<<dim3(16,32), blk, 0, stream>>>(qb, kb, vt, att);

        gemm3f<EPI_PART><<<dim3(64,1,4), blk, 0, stream>>>(att,4096,0, oV,4096,0,nullptr, part,1024,1048576, nullptr, 1024,4, 8);
        reduce_k<<<1024, blk, 0, stream>>>(part, 1048576, 4, r1);
        gemm3f<EPI_F32ADD><<<dim3(256,1,1), blk, 0, stream>>>(r1,1024,0, oUs,1024,0,nullptr, OUT,4096,0, X, 1024,1, 8);

        rmsnorm_k<<<1024, blk, 0, stream>>>(OUT, LN2, h2);
        gemm3f<EPI_PART><<<dim3(64,1,8), blk, 0, stream>>>(h2,4096,0, gV,4096,0,uV, part,1024,1048576, nullptr, 1024,4, 8);
        reduce_k<<<1024, blk, 0, stream>>>(part,              1048576, 4, gr);
        reduce_k<<<1024, blk, 0, stream>>>(part + 4L*1048576, 1048576, 4, ur);
        if (big) {
            gemm3b<EPI_SILU1><<<dim3(896,1,1), blk, 0, stream>>>(gr,1024,0, gUsb,1024,0,nullptr, hmid,14336,0, nullptr, 1024,1, 8);
            gemm3b<EPI_MUL  ><<<dim3(896,1,1), blk, 0, stream>>>(ur,1024,0, uUsb,1024,0,nullptr, hmid,14336,0, nullptr, 1024,1, 8);
            gemm3b<EPI_PART ><<<dim3(64,1,7), blk, 0, stream>>>(hmid,14336,0, dVb,14336,0,nullptr, part,1024,1048576, nullptr, 2048,7, 8);
        } else {
            gemm3f<EPI_SILU1><<<dim3(896,1,1), blk, 0, stream>>>(gr,1024,0, gUs,1024,0,nullptr, hmid,14336,0, nullptr, 1024,1, 8);
            gemm3f<EPI_MUL  ><<<dim3(896,1,1), blk, 0, stream>>>(ur,1024,0, uUs,1024,0,nullptr, hmid,14336,0, nullptr, 1024,1, 8);
            gemm3f<EPI_PART ><<<dim3(64,1,7), blk, 0, stream>>>(hmid,14336,0, dV,14336,0,nullptr, part,1024,1048576, nullptr, 2048,7, 8);
        }
        reduce_k<<<1024, blk, 0, stream>>>(part, 1048576, 7, dr);
        gemm3f<EPI_F32ADD><<<dim3(256,1,1), blk, 0, stream>>>(dr,1024,0, dUs,1024,0,nullptr, OUT,4096,0, OUT, 1024,1, 8);
        return;
    }

    // ---------------- fallback: gemm2 (fp32-B dbuf) path ----------------
    rmsnorm_k<<<1024, blk, 0, stream>>>(X, LN1, h1);
    gemm2<EPI_BF16><<<dim3(8,16,1), blk, 0, stream>>>(h1,4096,0, qV,4096,0,nullptr, xrq,2048,0, nullptr, 4096, 1);
    gemm2<EPI_BF16><<<dim3(8, 4,1), blk, 0, stream>>>(h1,4096,0, kV,4096,0,nullptr, xrk, 512,0, nullptr, 4096, 1);
    gemm2<EPI_BF16><<<dim3(8, 4,1), blk, 0, stream>>>(h1,4096,0, vV,4096,0,nullptr, xrv, 512,0, nullptr, 4096, 1);
    gemm2<EPI_BF16 ><<<dim3(8,1,32), blk, 0, stream>>>(xrq,2048,64, qUs,64,8192,nullptr, qb,128,131072, nullptr, 64, 1);
    gemm2<EPI_BF16 ><<<dim3(8,1, 8), blk, 0, stream>>>(xrk, 512,64, kUs,64,8192,nullptr, kb,128,131072, nullptr, 64, 1);
    gemm2<EPI_BF16T><<<dim3(8,1, 8), blk, 0, stream>>>(xrv, 512,64, vUs,64,8192,nullptr, vt,1024,131072, nullptr, 64, 1);
    rope_table_k<<<256, blk, 0, stream>>>(cs, sn);
    rope_k<<<8192, blk, 0, stream>>>(qb, cs, sn);
    rope_k<<<2048, blk, 0, stream>>>(kb, cs, sn);
    attn_k<<<dim3(16,32), blk, 0, stream>>>(qb, kb, vt, att);
    gemm2<EPI_BF16><<<dim3(8,8,1), blk, 0, stream>>>(att,4096,0, oV,4096,0,nullptr, r1,1024,0, nullptr, 4096, 1);
    gemm2<EPI_F32ADD><<<dim3(8,32,1), blk, 0, stream>>>(r1,1024,0, oUs,1024,0,nullptr, OUT,4096,0, X, 1024, 1);
    rmsnorm_k<<<1024, blk, 0, stream>>>(OUT, LN2, h2);
    gemm2<EPI_BF16><<<dim3(8,8,1), blk, 0, stream>>>(h2,4096,0, gV,4096,0,nullptr, gr,1024,0, nullptr, 4096, 1);
    gemm2<EPI_BF16><<<dim3(8,8,1), blk, 0, stream>>>(h2,4096,0, uV,4096,0,nullptr, ur,1024,0, nullptr, 4096, 1);
    gemm2<EPI_SILU1><<<dim3(8,112,1), blk, 0, stream>>>(gr,1024,0, gUs,1024,0,nullptr, hmid,14336,0, nullptr, 1024, 1);
    gemm2<EPI_MUL  ><<<dim3(8,112,1), blk, 0, stream>>>(ur,1024,0, uUs,1024,0,nullptr, hmid,14336,0, nullptr, 1024, 1);
    gemm2<EPI_BF16><<<dim3(8,8,1), blk, 0, stream>>>(hmid,14336,0, dV,14336,0,nullptr, dr,1024,0, nullptr, 14336, 1);
    gemm2<EPI_F32ADD><<<dim3(8,32,1), blk, 0, stream>>>(dr,1024,0, dUs,1024,0,nullptr, OUT,4096,0, OUT, 1024, 1);
}